// Round 16
// baseline (1108.890 us; speedup 1.0000x reference)
//
#include <hip/hip_runtime.h>
#include <hip/hip_fp16.h>
#include <stdint.h>

#define VV 32000
#define HH 256
#define BB 32
#define TT 128
#define VH 32256   // V + H
#define NTILE 4000 // 32 m-groups x 125 n-tiles(256)

typedef _Float16 f16;
typedef _Float16 f16x2 __attribute__((ext_vector_type(2)));
typedef _Float16 f16x8 __attribute__((ext_vector_type(8)));
typedef float f32x16 __attribute__((ext_vector_type(16)));

static __device__ __forceinline__ float dot2f(uint32_t w, uint32_t h, float acc){
  f16x2 a = __builtin_bit_cast(f16x2, w);
  f16x2 b = __builtin_bit_cast(f16x2, h);
#if __has_builtin(__builtin_amdgcn_fdot2)
  return __builtin_amdgcn_fdot2(a, b, acc, false);
#else
  acc = fmaf((float)a[0], (float)b[0], acc);
  acc = fmaf((float)a[1], (float)b[1], acc);
  return acc;
#endif
}

// ---------------- control-block init (done[t] at ctl[t*16], arrival=ctl[2048], tiles=ctl[2049])
__global__ void k_init(int* __restrict__ ctl){
  int i = blockIdx.x*1024 + threadIdx.x;
  if (i < 2050) ctl[i] = 0;
}

// ---------------- pack recurrent weights (512-thread layout, round-8 mapping)
__global__ void k_pack(const float* __restrict__ Wz, const float* __restrict__ Wr,
                       const float* __restrict__ Wh, uint32_t* __restrict__ Wpack){
  int idx = blockIdx.x*256 + threadIdx.x;
  if (idx >= 512*192) return;
  int t = idx / 192, rem = idx - t*192;
  int ol = rem >> 4, p = rem & 15;
  int ko = t & 7, no = t >> 3;
  int k = ko*32 + p*2;
  const float* W; int row;
  if (ol < 8){ int o = no*8 + ol; if (o < 256){ W = Wz; row = o; } else { W = Wr; row = o - 256; } }
  else { W = Wh; row = no*4 + (ol - 8); }
  float a = W[(size_t)row*VH + VV + k];
  float c = W[(size_t)row*VH + VV + k + 1];
  f16x2 v; v[0] = (f16)a; v[1] = (f16)c;
  Wpack[idx] = __builtin_bit_cast(uint32_t, v);
}

// ---------------- Wo f32 -> f16 (once)
__global__ void k_wo(const float* __restrict__ Wo, f16* __restrict__ Wof){
  int i = blockIdx.x*256 + threadIdx.x;
  const float4* s = (const float4*)Wo + (size_t)i*2;
  float4 f0 = s[0], f1 = s[1];
  f16x8 h;
  h[0]=(f16)f0.x; h[1]=(f16)f0.y; h[2]=(f16)f0.z; h[3]=(f16)f0.w;
  h[4]=(f16)f1.x; h[5]=(f16)f1.y; h[6]=(f16)f1.z; h[7]=(f16)f1.w;
  *(f16x8*)(Wof + (size_t)i*8) = h;
}

// ==== AGPR machinery (r13-validated): weights pinned in AGPRs, volatile reads per use ====
#define DECL16(P) uint32_t P##_0,P##_1,P##_2,P##_3,P##_4,P##_5,P##_6,P##_7, \
                           P##_8,P##_9,P##_10,P##_11,P##_12,P##_13,P##_14,P##_15;
#define LDQ(j,e0,e1,e2,e3) { uint4 v_ = src[j]; \
  asm("v_accvgpr_write_b32 %0, %1" : "=a"(e0) : "v"(v_.x)); \
  asm("v_accvgpr_write_b32 %0, %1" : "=a"(e1) : "v"(v_.y)); \
  asm("v_accvgpr_write_b32 %0, %1" : "=a"(e2) : "v"(v_.z)); \
  asm("v_accvgpr_write_b32 %0, %1" : "=a"(e3) : "v"(v_.w)); }
#define LDROW(r,P) LDQ(4*(r)+0,P##_0,P##_1,P##_2,P##_3)   LDQ(4*(r)+1,P##_4,P##_5,P##_6,P##_7) \
                   LDQ(4*(r)+2,P##_8,P##_9,P##_10,P##_11) LDQ(4*(r)+3,P##_12,P##_13,P##_14,P##_15)
#define RD(a_) __extension__({ uint32_t t_; \
  asm volatile("v_accvgpr_read_b32 %0, %1" : "=v"(t_) : "a"(a_)); t_; })
#define DOTP1(p) \
  a0 = dot2f(RD(w0_##p), hp[p], a0);  a1 = dot2f(RD(w1_##p), hp[p], a1); \
  a2 = dot2f(RD(w2_##p), hp[p], a2);  a3 = dot2f(RD(w3_##p), hp[p], a3); \
  a4 = dot2f(RD(w4_##p), hp[p], a4);  a5 = dot2f(RD(w5_##p), hp[p], a5); \
  a6 = dot2f(RD(w6_##p), hp[p], a6);  a7 = dot2f(RD(w7_##p), hp[p], a7);
#define DOTP2(p) \
  b0 = dot2f(RD(w8_##p),  rp[p], b0); b1 = dot2f(RD(w9_##p),  rp[p], b1); \
  b2 = dot2f(RD(w10_##p), rp[p], b2); b3 = dot2f(RD(w11_##p), rp[p], b3);
#define REDUCE(x) x += __shfl_xor(x,1); x += __shfl_xor(x,2); x += __shfl_xor(x,4);

// ---------------- fused: 256 blocks x 512 thr (1 block/CU). First 32 arrivals: producer.
__global__ __launch_bounds__(512)
__attribute__((amdgpu_waves_per_eu(2, 2)))
void k_main(const float* __restrict__ H0, const uint32_t* __restrict__ Wpack,
            const int* __restrict__ X,
            const float* __restrict__ Wz, const float* __restrict__ bz,
            const float* __restrict__ Wr, const float* __restrict__ br,
            const float* __restrict__ Wh, const float* __restrict__ bh,
            const f16* __restrict__ Wof, const float* __restrict__ bo,
            f16* __restrict__ Hn16, float* __restrict__ Y, float* __restrict__ hf_out,
            int* __restrict__ ctl){
  __shared__ __align__(16) f16 a_lds[128*128];     // 32 KB (consumer A)
  __shared__ __align__(16) f16 b_lds[256*128];     // 64 KB (consumer B)
  __shared__ __align__(16) uint32_t hs16[128];
  __shared__ __align__(16) f16 rHs16[256];
  __shared__ float hs32[256];
  __shared__ float z_s[256];
  __shared__ int tok_s[128];
  __shared__ int sh_role, sh_tile;
  const int tid = threadIdx.x;
  if (tid == 0) sh_role = atomicAdd(&ctl[2048], 1);
  __syncthreads();
  const int role = sh_role;

  if (role < BB){
    // ================= producer: recurrence for batch b (r13 explicit-AGPR) ==========
    const int b = role;
    const int ko = tid & 7, no = tid >> 3;

    DECL16(w0) DECL16(w1) DECL16(w2)  DECL16(w3)  DECL16(w4)  DECL16(w5)
    DECL16(w6) DECL16(w7) DECL16(w8)  DECL16(w9)  DECL16(w10) DECL16(w11)
    {
      const uint4* src = (const uint4*)(Wpack + (size_t)tid*192);
      LDROW(0,w0) LDROW(1,w1) LDROW(2,w2)   LDROW(3,w3)  LDROW(4,w4)  LDROW(5,w5)
      LDROW(6,w6) LDROW(7,w7) LDROW(8,w8)   LDROW(9,w9)  LDROW(10,w10) LDROW(11,w11)
    }

    if (tid < 256) hs32[tid] = H0[b*HH + tid];
    if (tid < 128) tok_s[tid] = X[b*TT + tid];
    __syncthreads();
    if (tid < 128){
      f16x2 v; v[0] = (f16)hs32[2*tid]; v[1] = (f16)hs32[2*tid+1];
      hs16[tid] = __builtin_bit_cast(uint32_t, v);
    }
    __syncthreads();

    // inline gather: per-lane gate column pointers + bias
    const int o1 = no*8 + ko;
    const float* W1p; float bias1;
    if (o1 < 256){ W1p = Wz + (size_t)o1*VH; bias1 = bz[o1]; }
    else         { W1p = Wr + (size_t)(o1-256)*VH; bias1 = br[o1-256]; }
    const int o2 = no*4 + (ko & 3);
    const float* W2p = Wh + (size_t)o2*VH;
    const float bias2 = bh[o2];
    {
      int tk0 = tok_s[0];
      float g1 = W1p[tk0] + bias1;
      float g2 = W2p[tk0] + bias2;
      float g1n = 0.f, g2n = 0.f;

      for (int t = 0; t < TT; t++){
        if (t < TT-1){
          int tk = tok_s[t+1];
          g1n = W1p[tk] + bias1;
          g2n = W2p[tk] + bias2;
        }

        // ---- phase 1: z (no<32) and r (no>=32), 8 outputs per group
        uint32_t hp[16];
        {
          const uint2* hsp = (const uint2*)hs16;
          #pragma unroll
          for (int j=0;j<8;j++){ uint2 v = hsp[ko*8 + j]; hp[2*j] = v.x; hp[2*j+1] = v.y; }
        }
        float a0=0.f,a1=0.f,a2=0.f,a3=0.f,a4=0.f,a5=0.f,a6=0.f,a7=0.f;
        DOTP1(0)  DOTP1(1)  DOTP1(2)  DOTP1(3)  DOTP1(4)  DOTP1(5)  DOTP1(6)  DOTP1(7)
        DOTP1(8)  DOTP1(9)  DOTP1(10) DOTP1(11) DOTP1(12) DOTP1(13) DOTP1(14) DOTP1(15)
        REDUCE(a0) REDUCE(a1) REDUCE(a2) REDUCE(a3) REDUCE(a4) REDUCE(a5) REDUCE(a6) REDUCE(a7)
        {
          float sel = a0;
          sel = (ko==1)?a1:sel; sel = (ko==2)?a2:sel; sel = (ko==3)?a3:sel;
          sel = (ko==4)?a4:sel; sel = (ko==5)?a5:sel; sel = (ko==6)?a6:sel; sel = (ko==7)?a7:sel;
          float pre = sel + g1;
          float s = 1.f / (1.f + __expf(-pre));
          int o = no*8 + ko;
          if (no < 32){
            z_s[o] = s;
          } else {
            int op = o - 256;
            rHs16[op] = (f16)(s * hs32[op]);
          }
        }
        __syncthreads();

        // ---- phase 2
        uint32_t rp[16];
        {
          const uint2* rpp = (const uint2*)rHs16;
          #pragma unroll
          for (int j=0;j<8;j++){ uint2 v = rpp[ko*8 + j]; rp[2*j] = v.x; rp[2*j+1] = v.y; }
        }
        float b0=0.f,b1=0.f,b2=0.f,b3=0.f;
        DOTP2(0)  DOTP2(1)  DOTP2(2)  DOTP2(3)  DOTP2(4)  DOTP2(5)  DOTP2(6)  DOTP2(7)
        DOTP2(8)  DOTP2(9)  DOTP2(10) DOTP2(11) DOTP2(12) DOTP2(13) DOTP2(14) DOTP2(15)
        REDUCE(b0) REDUCE(b1) REDUCE(b2) REDUCE(b3)
        if (ko < 4){
          float sel = b0;
          sel = (ko==1)?b1:sel; sel = (ko==2)?b2:sel; sel = (ko==3)?b3:sel;
          int o = no*4 + ko;
          float pre = sel + g2;
          float ax = fabsf(pre);
          float e = __expf(2.f*ax);
          float th = 1.f - 2.f/(e + 1.f);      // tanh(|x|), safe at inf
          th = copysignf(th, pre);
          float z = z_s[o];
          float hn = z*th + (1.f - z)*hs32[o];
          hs32[o] = hn;
          ((f16*)hs16)[o] = (f16)hn;
          Hn16[(size_t)(t*BB + b)*HH + o] = (f16)hn;
          if (t == TT-1) hf_out[b*HH + o] = hn;
        }
        g1 = g1n; g2 = g2n;
        __syncthreads();
        if (tid == 0){ __threadfence(); atomicAdd(&ctl[t*16], 1); }
      }
    }
  }

  // ================= consumer loop (all blocks; producers join for the tail) =========
  {
    const int lane = tid & 63, wid = tid >> 6;
    const int wm = wid & 1, wn = wid >> 1;       // 2M x 4N waves, each 64x64
    const int arow = tid >> 2, aseg = tid & 3;   // A: 128 rows x 4 seg (32 f16 each)
    const int brow = tid >> 1, bseg = tid & 1;   // B: 256 rows x 2 seg (64 f16 each)
    int fenced_t = -1;
    for (;;){
      if (tid == 0) sh_tile = atomicAdd(&ctl[2049], 1);
      __syncthreads();
      const int tile = sh_tile;
      if (tile >= NTILE) break;
      const int mg = tile / 125;
      const int ng = tile - mg*125;
      const int m0 = mg*128, n0 = ng*256;
      const int t_need = mg*4 + 3;
      if (tid == 0 && t_need > fenced_t){
        while (atomicAdd(&ctl[t_need*16], 0) < BB) __builtin_amdgcn_s_sleep(64);
        __threadfence();           // acquire before reading Hn16
        fenced_t = t_need;
      }
      __syncthreads();

      f32x16 acc[2][2];
      {
        f32x16 z = {0.f};
        acc[0][0]=z; acc[0][1]=z; acc[1][0]=z; acc[1][1]=z;
      }

      #pragma unroll 1
      for (int kt=0; kt<2; kt++){
        {
          const uint4* asrc = (const uint4*)(Hn16 + (size_t)(m0+arow)*HH + kt*128 + aseg*32);
          #pragma unroll
          for (int j=0;j<4;j++){
            uint4 v = asrc[j];
            int byte = arow*256 + ((aseg*64 + j*16) ^ ((arow&15)<<4));
            *(uint4*)((char*)a_lds + byte) = v;
          }
          const uint4* bsrc = (const uint4*)(Wof + (size_t)(n0+brow)*HH + kt*128 + bseg*64);
          #pragma unroll
          for (int j=0;j<8;j++){
            uint4 v = bsrc[j];
            int byte = brow*256 + ((bseg*128 + j*16) ^ ((brow&15)<<4));
            *(uint4*)((char*)b_lds + byte) = v;
          }
        }
        __syncthreads();
        #pragma unroll
        for (int kk=0; kk<8; kk++){
          const int kbyte = kk*32 + (lane>>5)*16;
          f16x8 af[2], bf[2];
          #pragma unroll
          for (int mi=0;mi<2;mi++){
            int row = wm*64 + mi*32 + (lane&31);
            int byte = row*256 + (kbyte ^ ((row&15)<<4));
            af[mi] = *(const f16x8*)((const char*)a_lds + byte);
          }
          #pragma unroll
          for (int nj=0;nj<2;nj++){
            int nl = wn*64 + nj*32 + (lane&31);
            int byte = nl*256 + (kbyte ^ ((nl&15)<<4));
            bf[nj] = *(const f16x8*)((const char*)b_lds + byte);
          }
          #pragma unroll
          for (int mi=0;mi<2;mi++)
            #pragma unroll
            for (int nj=0;nj<2;nj++)
              acc[mi][nj] = __builtin_amdgcn_mfma_f32_32x32x16_f16(af[mi], bf[nj], acc[mi][nj], 0, 0, 0);
        }
        __syncthreads();
      }
      // epilogue: 32x32 C/D map (r15-validated): col=lane&31, row=(r&3)+8*(r>>2)+4*(lane>>5)
      #pragma unroll
      for (int nj=0;nj<2;nj++){
        const int col = n0 + wn*64 + nj*32 + (lane & 31);
        const float bov = bo[col];
        #pragma unroll
        for (int mi=0;mi<2;mi++){
          const int rbase = m0 + wm*64 + mi*32 + 4*(lane>>5);
          #pragma unroll
          for (int r=0;r<16;r++){
            int row = rbase + (r&3) + 8*(r>>2);
            Y[(size_t)row*VV + col] = acc[mi][nj][r] + bov;
          }
        }
      }
    }
  }
}

extern "C" void kernel_launch(void* const* d_in, const int* in_sizes, int n_in,
                              void* d_out, int out_size, void* d_ws, size_t ws_size,
                              hipStream_t stream){
  const int*   X  = (const int*)d_in[0];
  const float* H0 = (const float*)d_in[1];
  const float* Wz = (const float*)d_in[2];
  const float* bz = (const float*)d_in[3];
  const float* Wr = (const float*)d_in[4];
  const float* br = (const float*)d_in[5];
  const float* Wh = (const float*)d_in[6];
  const float* bh = (const float*)d_in[7];
  const float* Wo = (const float*)d_in[8];
  const float* bo = (const float*)d_in[9];
  float* out = (float*)d_out;

  char* ws = (char*)d_ws;
  uint32_t* Wpack = (uint32_t*)ws;                  //    393,216 B
  f16*      Hn16  = (f16*)(ws + 393216);            //  2,097,152 B
  f16*      Wof   = (f16*)(ws + 2490368);           // 16,384,000 B
  int*      ctl   = (int*)(ws + 18874368);          //      8,200 B

  k_init<<<3, 1024, 0, stream>>>(ctl);
  k_pack<<<384, 256, 0, stream>>>(Wz, Wr, Wh, Wpack);
  k_wo<<<4000, 256, 0, stream>>>(Wo, Wof);
  k_main<<<256, 512, 0, stream>>>(H0, Wpack, X, Wz, bz, Wr, br, Wh, bh,
                                  Wof, bo, Hn16, out, out + 131072000LL, ctl);
}

// Round 17
// 842.794 us; speedup vs baseline: 1.3157x; 1.3157x over previous
//
#include <hip/hip_runtime.h>
#include <hip/hip_fp16.h>
#include <stdint.h>

#define VV 32000
#define HH 256
#define BB 32
#define TT 128
#define VH 32256   // V + H
#define NTILE 4000 // 32 m-groups x 125 n-tiles(256)

typedef _Float16 f16;
typedef _Float16 f16x2 __attribute__((ext_vector_type(2)));
typedef _Float16 f16x8 __attribute__((ext_vector_type(8)));
typedef float f32x16 __attribute__((ext_vector_type(16)));

static __device__ __forceinline__ float dot2f(uint32_t w, uint32_t h, float acc){
  f16x2 a = __builtin_bit_cast(f16x2, w);
  f16x2 b = __builtin_bit_cast(f16x2, h);
#if __has_builtin(__builtin_amdgcn_fdot2)
  return __builtin_amdgcn_fdot2(a, b, acc, false);
#else
  acc = fmaf((float)a[0], (float)b[0], acc);
  acc = fmaf((float)a[1], (float)b[1], acc);
  return acc;
#endif
}

// ---------------- control-block init (done[t] at ctl[t*32] — 128-B padded; arrival=ctl[4096], tiles=ctl[4097])
__global__ void k_init(int* __restrict__ ctl){
  int i = blockIdx.x*1024 + threadIdx.x;
  if (i < 4100) ctl[i] = 0;
}

// ---------------- gather: g[t*32+b][o] = W_gate[row][tok] + bias  (coalesced, precomputed)
__global__ void k_gather(const int* __restrict__ X,
                         const float* __restrict__ Wz, const float* __restrict__ bz,
                         const float* __restrict__ Wr, const float* __restrict__ br,
                         const float* __restrict__ Wh, const float* __restrict__ bh,
                         float* __restrict__ g_buf){
  int tb = blockIdx.x;              // t*32 + b
  int t = tb >> 5, b = tb & 31;
  int tok = X[b*TT + t];
  int o = threadIdx.x;              // 0..255
  g_buf[(size_t)tb*768 + o]       = Wz[(size_t)o*VH + tok] + bz[o];
  g_buf[(size_t)tb*768 + 256 + o] = Wr[(size_t)o*VH + tok] + br[o];
  g_buf[(size_t)tb*768 + 512 + o] = Wh[(size_t)o*VH + tok] + bh[o];
}

// ---------------- pack recurrent weights (512-thread layout, round-8 mapping)
__global__ void k_pack(const float* __restrict__ Wz, const float* __restrict__ Wr,
                       const float* __restrict__ Wh, uint32_t* __restrict__ Wpack){
  int idx = blockIdx.x*256 + threadIdx.x;
  if (idx >= 512*192) return;
  int t = idx / 192, rem = idx - t*192;
  int ol = rem >> 4, p = rem & 15;
  int ko = t & 7, no = t >> 3;
  int k = ko*32 + p*2;
  const float* W; int row;
  if (ol < 8){ int o = no*8 + ol; if (o < 256){ W = Wz; row = o; } else { W = Wr; row = o - 256; } }
  else { W = Wh; row = no*4 + (ol - 8); }
  float a = W[(size_t)row*VH + VV + k];
  float c = W[(size_t)row*VH + VV + k + 1];
  f16x2 v; v[0] = (f16)a; v[1] = (f16)c;
  Wpack[idx] = __builtin_bit_cast(uint32_t, v);
}

// ---------------- Wo f32 -> f16 (once)
__global__ void k_wo(const float* __restrict__ Wo, f16* __restrict__ Wof){
  int i = blockIdx.x*256 + threadIdx.x;
  const float4* s = (const float4*)Wo + (size_t)i*2;
  float4 f0 = s[0], f1 = s[1];
  f16x8 h;
  h[0]=(f16)f0.x; h[1]=(f16)f0.y; h[2]=(f16)f0.z; h[3]=(f16)f0.w;
  h[4]=(f16)f1.x; h[5]=(f16)f1.y; h[6]=(f16)f1.z; h[7]=(f16)f1.w;
  *(f16x8*)(Wof + (size_t)i*8) = h;
}

// ==== AGPR machinery (r13-validated): weights pinned in AGPRs, volatile reads per use ====
#define DECL16(P) uint32_t P##_0,P##_1,P##_2,P##_3,P##_4,P##_5,P##_6,P##_7, \
                           P##_8,P##_9,P##_10,P##_11,P##_12,P##_13,P##_14,P##_15;
#define LDQ(j,e0,e1,e2,e3) { uint4 v_ = src[j]; \
  asm("v_accvgpr_write_b32 %0, %1" : "=a"(e0) : "v"(v_.x)); \
  asm("v_accvgpr_write_b32 %0, %1" : "=a"(e1) : "v"(v_.y)); \
  asm("v_accvgpr_write_b32 %0, %1" : "=a"(e2) : "v"(v_.z)); \
  asm("v_accvgpr_write_b32 %0, %1" : "=a"(e3) : "v"(v_.w)); }
#define LDROW(r,P) LDQ(4*(r)+0,P##_0,P##_1,P##_2,P##_3)   LDQ(4*(r)+1,P##_4,P##_5,P##_6,P##_7) \
                   LDQ(4*(r)+2,P##_8,P##_9,P##_10,P##_11) LDQ(4*(r)+3,P##_12,P##_13,P##_14,P##_15)
#define RD(a_) __extension__({ uint32_t t_; \
  asm volatile("v_accvgpr_read_b32 %0, %1" : "=v"(t_) : "a"(a_)); t_; })
#define DOTP1(p) \
  a0 = dot2f(RD(w0_##p), hp[p], a0);  a1 = dot2f(RD(w1_##p), hp[p], a1); \
  a2 = dot2f(RD(w2_##p), hp[p], a2);  a3 = dot2f(RD(w3_##p), hp[p], a3); \
  a4 = dot2f(RD(w4_##p), hp[p], a4);  a5 = dot2f(RD(w5_##p), hp[p], a5); \
  a6 = dot2f(RD(w6_##p), hp[p], a6);  a7 = dot2f(RD(w7_##p), hp[p], a7);
#define DOTP2(p) \
  b0 = dot2f(RD(w8_##p),  rp[p], b0); b1 = dot2f(RD(w9_##p),  rp[p], b1); \
  b2 = dot2f(RD(w10_##p), rp[p], b2); b3 = dot2f(RD(w11_##p), rp[p], b3);
#define REDUCE(x) x += __shfl_xor(x,1); x += __shfl_xor(x,2); x += __shfl_xor(x,4);

// ---------------- fused: 256 blocks x 512 thr (1 block/CU). First 32 arrivals: producer.
__global__ __launch_bounds__(512)
__attribute__((amdgpu_waves_per_eu(2, 2)))
void k_main(const float* __restrict__ H0, const uint32_t* __restrict__ Wpack,
            const float* __restrict__ g_buf,
            const f16* __restrict__ Wof, const float* __restrict__ bo,
            f16* __restrict__ Hn16, float* __restrict__ Y, float* __restrict__ hf_out,
            int* __restrict__ ctl){
  __shared__ __align__(16) f16 a_lds[128*128];     // 32 KB (consumer A)
  __shared__ __align__(16) f16 b_lds[256*128];     // 64 KB (consumer B)
  __shared__ __align__(16) uint32_t hs16[128];
  __shared__ __align__(16) f16 rHs16[256];
  __shared__ float hs32[256];
  __shared__ float z_s[256];
  __shared__ int sh_role, sh_tile;
  const int tid = threadIdx.x;
  if (tid == 0) sh_role = atomicAdd(&ctl[4096], 1);
  __syncthreads();
  const int role = sh_role;

  if (role < BB){
    // ================= producer: recurrence for batch b (r13 explicit-AGPR + g_buf) ====
    const int b = role;
    const int ko = tid & 7, no = tid >> 3;

    DECL16(w0) DECL16(w1) DECL16(w2)  DECL16(w3)  DECL16(w4)  DECL16(w5)
    DECL16(w6) DECL16(w7) DECL16(w8)  DECL16(w9)  DECL16(w10) DECL16(w11)
    {
      const uint4* src = (const uint4*)(Wpack + (size_t)tid*192);
      LDROW(0,w0) LDROW(1,w1) LDROW(2,w2)   LDROW(3,w3)  LDROW(4,w4)  LDROW(5,w5)
      LDROW(6,w6) LDROW(7,w7) LDROW(8,w8)   LDROW(9,w9)  LDROW(10,w10) LDROW(11,w11)
    }

    if (tid < 256) hs32[tid] = H0[b*HH + tid];
    __syncthreads();
    if (tid < 128){
      f16x2 v; v[0] = (f16)hs32[2*tid]; v[1] = (f16)hs32[2*tid+1];
      hs16[tid] = __builtin_bit_cast(uint32_t, v);
    }
    __syncthreads();

    const int gi1 = no*8 + ko;
    const int gi2 = 512 + no*4 + (ko & 3);
    float g1 = g_buf[(size_t)b*768 + gi1];
    float g2 = g_buf[(size_t)b*768 + gi2];
    float g1n = 0.f, g2n = 0.f;

    for (int t = 0; t < TT; t++){
      if (t < TT-1){
        const float* gn = g_buf + (size_t)((t+1)*BB + b)*768;
        g1n = gn[gi1];
        g2n = gn[gi2];
      }

      // ---- phase 1: z (no<32) and r (no>=32), 8 outputs per group
      uint32_t hp[16];
      {
        const uint2* hsp = (const uint2*)hs16;
        #pragma unroll
        for (int j=0;j<8;j++){ uint2 v = hsp[ko*8 + j]; hp[2*j] = v.x; hp[2*j+1] = v.y; }
      }
      float a0=0.f,a1=0.f,a2=0.f,a3=0.f,a4=0.f,a5=0.f,a6=0.f,a7=0.f;
      DOTP1(0)  DOTP1(1)  DOTP1(2)  DOTP1(3)  DOTP1(4)  DOTP1(5)  DOTP1(6)  DOTP1(7)
      DOTP1(8)  DOTP1(9)  DOTP1(10) DOTP1(11) DOTP1(12) DOTP1(13) DOTP1(14) DOTP1(15)
      REDUCE(a0) REDUCE(a1) REDUCE(a2) REDUCE(a3) REDUCE(a4) REDUCE(a5) REDUCE(a6) REDUCE(a7)
      {
        float sel = a0;
        sel = (ko==1)?a1:sel; sel = (ko==2)?a2:sel; sel = (ko==3)?a3:sel;
        sel = (ko==4)?a4:sel; sel = (ko==5)?a5:sel; sel = (ko==6)?a6:sel; sel = (ko==7)?a7:sel;
        float pre = sel + g1;
        float s = 1.f / (1.f + __expf(-pre));
        int o = no*8 + ko;
        if (no < 32){
          z_s[o] = s;
        } else {
          int op = o - 256;
          rHs16[op] = (f16)(s * hs32[op]);
        }
      }
      __syncthreads();

      // ---- phase 2
      uint32_t rp[16];
      {
        const uint2* rpp = (const uint2*)rHs16;
        #pragma unroll
        for (int j=0;j<8;j++){ uint2 v = rpp[ko*8 + j]; rp[2*j] = v.x; rp[2*j+1] = v.y; }
      }
      float b0=0.f,b1=0.f,b2=0.f,b3=0.f;
      DOTP2(0)  DOTP2(1)  DOTP2(2)  DOTP2(3)  DOTP2(4)  DOTP2(5)  DOTP2(6)  DOTP2(7)
      DOTP2(8)  DOTP2(9)  DOTP2(10) DOTP2(11) DOTP2(12) DOTP2(13) DOTP2(14) DOTP2(15)
      REDUCE(b0) REDUCE(b1) REDUCE(b2) REDUCE(b3)
      if (ko < 4){
        float sel = b0;
        sel = (ko==1)?b1:sel; sel = (ko==2)?b2:sel; sel = (ko==3)?b3:sel;
        int o = no*4 + ko;
        float pre = sel + g2;
        float ax = fabsf(pre);
        float e = __expf(2.f*ax);
        float th = 1.f - 2.f/(e + 1.f);      // tanh(|x|), safe at inf
        th = copysignf(th, pre);
        float z = z_s[o];
        float hn = z*th + (1.f - z)*hs32[o];
        hs32[o] = hn;
        ((f16*)hs16)[o] = (f16)hn;
        Hn16[(size_t)(t*BB + b)*HH + o] = (f16)hn;
        if (t == TT-1) hf_out[b*HH + o] = hn;
      }
      g1 = g1n; g2 = g2n;
      __syncthreads();
      if (tid == 0){ __threadfence(); atomicAdd(&ctl[t*32], 1); }
    }
  }

  // ================= consumer loop (all blocks; producers join for the tail) =========
  {
    const int lane = tid & 63, wid = tid >> 6;
    const int wm = wid & 1, wn = wid >> 1;       // 2M x 4N waves, each 64x64
    const int arow = tid >> 2, aseg = tid & 3;   // A: 128 rows x 4 seg (32 f16 each)
    const int brow = tid >> 1, bseg = tid & 1;   // B: 256 rows x 2 seg (64 f16 each)
    int fenced_t = -1;
    for (;;){
      if (tid == 0) sh_tile = atomicAdd(&ctl[4097], 1);
      __syncthreads();
      const int tile = sh_tile;
      if (tile >= NTILE) break;
      const int mg = tile / 125;
      const int ng = tile - mg*125;
      const int m0 = mg*128, n0 = ng*256;
      const int t_need = mg*4 + 3;
      if (tid == 0 && t_need > fenced_t){
        while (atomicAdd(&ctl[t_need*32], 0) < BB) __builtin_amdgcn_s_sleep(64);
        __threadfence();           // acquire before reading Hn16
        fenced_t = t_need;
      }
      __syncthreads();

      f32x16 acc[2][2];
      {
        f32x16 z = {0.f};
        acc[0][0]=z; acc[0][1]=z; acc[1][0]=z; acc[1][1]=z;
      }

      #pragma unroll 1
      for (int kt=0; kt<2; kt++){
        {
          const uint4* asrc = (const uint4*)(Hn16 + (size_t)(m0+arow)*HH + kt*128 + aseg*32);
          #pragma unroll
          for (int j=0;j<4;j++){
            uint4 v = asrc[j];
            int byte = arow*256 + ((aseg*64 + j*16) ^ ((arow&15)<<4));
            *(uint4*)((char*)a_lds + byte) = v;
          }
          const uint4* bsrc = (const uint4*)(Wof + (size_t)(n0+brow)*HH + kt*128 + bseg*64);
          #pragma unroll
          for (int j=0;j<8;j++){
            uint4 v = bsrc[j];
            int byte = brow*256 + ((bseg*128 + j*16) ^ ((brow&15)<<4));
            *(uint4*)((char*)b_lds + byte) = v;
          }
        }
        __syncthreads();
        #pragma unroll
        for (int kk=0; kk<8; kk++){
          const int kbyte = kk*32 + (lane>>5)*16;
          f16x8 af[2], bf[2];
          #pragma unroll
          for (int mi=0;mi<2;mi++){
            int row = wm*64 + mi*32 + (lane&31);
            int byte = row*256 + (kbyte ^ ((row&15)<<4));
            af[mi] = *(const f16x8*)((const char*)a_lds + byte);
          }
          #pragma unroll
          for (int nj=0;nj<2;nj++){
            int nl = wn*64 + nj*32 + (lane&31);
            int byte = nl*256 + (kbyte ^ ((nl&15)<<4));
            bf[nj] = *(const f16x8*)((const char*)b_lds + byte);
          }
          #pragma unroll
          for (int mi=0;mi<2;mi++)
            #pragma unroll
            for (int nj=0;nj<2;nj++)
              acc[mi][nj] = __builtin_amdgcn_mfma_f32_32x32x16_f16(af[mi], bf[nj], acc[mi][nj], 0, 0, 0);
        }
        __syncthreads();
      }
      // epilogue: 32x32 C/D map (r15-validated): col=lane&31, row=(r&3)+8*(r>>2)+4*(lane>>5)
      #pragma unroll
      for (int nj=0;nj<2;nj++){
        const int col = n0 + wn*64 + nj*32 + (lane & 31);
        const float bov = bo[col];
        #pragma unroll
        for (int mi=0;mi<2;mi++){
          const int rbase = m0 + wm*64 + mi*32 + 4*(lane>>5);
          #pragma unroll
          for (int r=0;r<16;r++){
            int row = rbase + (r&3) + 8*(r>>2);
            Y[(size_t)row*VV + col] = acc[mi][nj][r] + bov;
          }
        }
      }
    }
  }
}

extern "C" void kernel_launch(void* const* d_in, const int* in_sizes, int n_in,
                              void* d_out, int out_size, void* d_ws, size_t ws_size,
                              hipStream_t stream){
  const int*   X  = (const int*)d_in[0];
  const float* H0 = (const float*)d_in[1];
  const float* Wz = (const float*)d_in[2];
  const float* bz = (const float*)d_in[3];
  const float* Wr = (const float*)d_in[4];
  const float* br = (const float*)d_in[5];
  const float* Wh = (const float*)d_in[6];
  const float* bh = (const float*)d_in[7];
  const float* Wo = (const float*)d_in[8];
  const float* bo = (const float*)d_in[9];
  float* out = (float*)d_out;

  char* ws = (char*)d_ws;
  int*      ctl   = (int*)ws;                       //     16,512 B (padded)
  uint32_t* Wpack = (uint32_t*)(ws + 16512);        //    393,216 B
  f16*      Hn16  = (f16*)(ws + 409728);            //  2,097,152 B
  f16*      Wof   = (f16*)(ws + 2506880);           // 16,384,000 B
  float*    g_buf = (float*)(ws + 18890880);        // 12,582,912 B

  k_init<<<5, 1024, 0, stream>>>(ctl);
  k_gather<<<4096, 256, 0, stream>>>(X, Wz, bz, Wr, br, Wh, bh, g_buf);
  k_pack<<<384, 256, 0, stream>>>(Wz, Wr, Wh, Wpack);
  k_wo<<<4000, 256, 0, stream>>>(Wo, Wof);
  k_main<<<256, 512, 0, stream>>>(H0, Wpack, g_buf, Wof, bo, Hn16, out, out + 131072000LL, ctl);
}

// Round 18
// 533.864 us; speedup vs baseline: 2.0771x; 1.5787x over previous
//
#include <hip/hip_runtime.h>
#include <hip/hip_fp16.h>
#include <stdint.h>

#define VV 32000
#define HH 256
#define BB 32
#define TT 128
#define VH 32256   // V + H
#define NTILE 4000 // 32 m-groups x 125 n-tiles(256)

typedef _Float16 f16;
typedef _Float16 f16x2 __attribute__((ext_vector_type(2)));
typedef _Float16 f16x8 __attribute__((ext_vector_type(8)));
typedef float f32x16 __attribute__((ext_vector_type(16)));
typedef unsigned long long u64;

static __device__ __forceinline__ float dot2f(uint32_t w, uint32_t h, float acc){
  f16x2 a = __builtin_bit_cast(f16x2, w);
  f16x2 b = __builtin_bit_cast(f16x2, h);
#if __has_builtin(__builtin_amdgcn_fdot2)
  return __builtin_amdgcn_fdot2(a, b, acc, false);
#else
  acc = fmaf((float)a[0], (float)b[0], acc);
  acc = fmaf((float)a[1], (float)b[1], acc);
  return acc;
#endif
}

// ---------------- control-block init (done[t] at ctl[t*32] — 128-B padded; arrival=ctl[4096], tiles=ctl[4097])
__global__ void k_init(int* __restrict__ ctl){
  int i = blockIdx.x*1024 + threadIdx.x;
  if (i < 4100) ctl[i] = 0;
}

// ---------------- gather: g[t*32+b][o] = W_gate[row][tok] + bias  (coalesced, precomputed)
__global__ void k_gather(const int* __restrict__ X,
                         const float* __restrict__ Wz, const float* __restrict__ bz,
                         const float* __restrict__ Wr, const float* __restrict__ br,
                         const float* __restrict__ Wh, const float* __restrict__ bh,
                         float* __restrict__ g_buf){
  int tb = blockIdx.x;              // t*32 + b
  int t = tb >> 5, b = tb & 31;
  int tok = X[b*TT + t];
  int o = threadIdx.x;              // 0..255
  g_buf[(size_t)tb*768 + o]       = Wz[(size_t)o*VH + tok] + bz[o];
  g_buf[(size_t)tb*768 + 256 + o] = Wr[(size_t)o*VH + tok] + br[o];
  g_buf[(size_t)tb*768 + 512 + o] = Wh[(size_t)o*VH + tok] + bh[o];
}

// ---------------- pack recurrent weights (512-thread layout, round-8 mapping)
__global__ void k_pack(const float* __restrict__ Wz, const float* __restrict__ Wr,
                       const float* __restrict__ Wh, uint32_t* __restrict__ Wpack){
  int idx = blockIdx.x*256 + threadIdx.x;
  if (idx >= 512*192) return;
  int t = idx / 192, rem = idx - t*192;
  int ol = rem >> 4, p = rem & 15;
  int ko = t & 7, no = t >> 3;
  int k = ko*32 + p*2;
  const float* W; int row;
  if (ol < 8){ int o = no*8 + ol; if (o < 256){ W = Wz; row = o; } else { W = Wr; row = o - 256; } }
  else { W = Wh; row = no*4 + (ol - 8); }
  float a = W[(size_t)row*VH + VV + k];
  float c = W[(size_t)row*VH + VV + k + 1];
  f16x2 v; v[0] = (f16)a; v[1] = (f16)c;
  Wpack[idx] = __builtin_bit_cast(uint32_t, v);
}

// ---------------- Wo f32 -> f16 (once)
__global__ void k_wo(const float* __restrict__ Wo, f16* __restrict__ Wof){
  int i = blockIdx.x*256 + threadIdx.x;
  const float4* s = (const float4*)Wo + (size_t)i*2;
  float4 f0 = s[0], f1 = s[1];
  f16x8 h;
  h[0]=(f16)f0.x; h[1]=(f16)f0.y; h[2]=(f16)f0.z; h[3]=(f16)f0.w;
  h[4]=(f16)f1.x; h[5]=(f16)f1.y; h[6]=(f16)f1.z; h[7]=(f16)f1.w;
  *(f16x8*)(Wof + (size_t)i*8) = h;
}

// ==== AGPR machinery (r13-validated): weights pinned in AGPRs, volatile reads per use ====
#define DECL16(P) uint32_t P##_0,P##_1,P##_2,P##_3,P##_4,P##_5,P##_6,P##_7, \
                           P##_8,P##_9,P##_10,P##_11,P##_12,P##_13,P##_14,P##_15;
#define LDQ(j,e0,e1,e2,e3) { uint4 v_ = src[j]; \
  asm("v_accvgpr_write_b32 %0, %1" : "=a"(e0) : "v"(v_.x)); \
  asm("v_accvgpr_write_b32 %0, %1" : "=a"(e1) : "v"(v_.y)); \
  asm("v_accvgpr_write_b32 %0, %1" : "=a"(e2) : "v"(v_.z)); \
  asm("v_accvgpr_write_b32 %0, %1" : "=a"(e3) : "v"(v_.w)); }
#define LDROW(r,P) LDQ(4*(r)+0,P##_0,P##_1,P##_2,P##_3)   LDQ(4*(r)+1,P##_4,P##_5,P##_6,P##_7) \
                   LDQ(4*(r)+2,P##_8,P##_9,P##_10,P##_11) LDQ(4*(r)+3,P##_12,P##_13,P##_14,P##_15)
#define RD(a_) __extension__({ uint32_t t_; \
  asm volatile("v_accvgpr_read_b32 %0, %1" : "=v"(t_) : "a"(a_)); t_; })
#define DOTP1(p) \
  a0 = dot2f(RD(w0_##p), hp[p], a0);  a1 = dot2f(RD(w1_##p), hp[p], a1); \
  a2 = dot2f(RD(w2_##p), hp[p], a2);  a3 = dot2f(RD(w3_##p), hp[p], a3); \
  a4 = dot2f(RD(w4_##p), hp[p], a4);  a5 = dot2f(RD(w5_##p), hp[p], a5); \
  a6 = dot2f(RD(w6_##p), hp[p], a6);  a7 = dot2f(RD(w7_##p), hp[p], a7);
#define DOTP2(p) \
  b0 = dot2f(RD(w8_##p),  rp[p], b0); b1 = dot2f(RD(w9_##p),  rp[p], b1); \
  b2 = dot2f(RD(w10_##p), rp[p], b2); b3 = dot2f(RD(w11_##p), rp[p], b3);
#define REDUCE(x) x += __shfl_xor(x,1); x += __shfl_xor(x,2); x += __shfl_xor(x,4);

// ---------------- fused: 256 blocks x 512 thr (1 block/CU). First 32 arrivals: producer.
__global__ __launch_bounds__(512)
__attribute__((amdgpu_waves_per_eu(2, 2)))
void k_main(const float* __restrict__ H0, const uint32_t* __restrict__ Wpack,
            const float* __restrict__ g_buf,
            const f16* __restrict__ Wof, const float* __restrict__ bo,
            f16* __restrict__ Hn16, float* __restrict__ Y, float* __restrict__ hf_out,
            int* __restrict__ ctl){
  __shared__ __align__(16) f16 a_lds[128*128];     // 32 KB (consumer A)
  __shared__ __align__(16) f16 b_lds[256*128];     // 64 KB (consumer B)
  __shared__ __align__(16) uint32_t hs16[128];
  __shared__ __align__(16) f16 rHs16[256];
  __shared__ float hs32[256];
  __shared__ float z_s[256];
  __shared__ int sh_role, sh_tile;
  const int tid = threadIdx.x;
  if (tid == 0) sh_role = atomicAdd(&ctl[4096], 1);
  __syncthreads();
  const int role = sh_role;

  if (role < BB){
    // ================= producer: recurrence for batch b (explicit-AGPR + g_buf) =======
    const int b = role;
    const int ko = tid & 7, no = tid >> 3;

    DECL16(w0) DECL16(w1) DECL16(w2)  DECL16(w3)  DECL16(w4)  DECL16(w5)
    DECL16(w6) DECL16(w7) DECL16(w8)  DECL16(w9)  DECL16(w10) DECL16(w11)
    {
      const uint4* src = (const uint4*)(Wpack + (size_t)tid*192);
      LDROW(0,w0) LDROW(1,w1) LDROW(2,w2)   LDROW(3,w3)  LDROW(4,w4)  LDROW(5,w5)
      LDROW(6,w6) LDROW(7,w7) LDROW(8,w8)   LDROW(9,w9)  LDROW(10,w10) LDROW(11,w11)
    }

    if (tid < 256) hs32[tid] = H0[b*HH + tid];
    __syncthreads();
    if (tid < 128){
      f16x2 v; v[0] = (f16)hs32[2*tid]; v[1] = (f16)hs32[2*tid+1];
      hs16[tid] = __builtin_bit_cast(uint32_t, v);
    }
    __syncthreads();

    const int gi1 = no*8 + ko;
    const int gi2 = 512 + no*4 + (ko & 3);
    float g1 = g_buf[(size_t)b*768 + gi1];
    float g2 = g_buf[(size_t)b*768 + gi2];
    float g1n = 0.f, g2n = 0.f;

    for (int t = 0; t < TT; t++){
      if (t < TT-1){
        const float* gn = g_buf + (size_t)((t+1)*BB + b)*768;
        g1n = gn[gi1];
        g2n = gn[gi2];
      }

      // ---- phase 1: z (no<32) and r (no>=32), 8 outputs per group
      uint32_t hp[16];
      {
        const uint2* hsp = (const uint2*)hs16;
        #pragma unroll
        for (int j=0;j<8;j++){ uint2 v = hsp[ko*8 + j]; hp[2*j] = v.x; hp[2*j+1] = v.y; }
      }
      float a0=0.f,a1=0.f,a2=0.f,a3=0.f,a4=0.f,a5=0.f,a6=0.f,a7=0.f;
      DOTP1(0)  DOTP1(1)  DOTP1(2)  DOTP1(3)  DOTP1(4)  DOTP1(5)  DOTP1(6)  DOTP1(7)
      DOTP1(8)  DOTP1(9)  DOTP1(10) DOTP1(11) DOTP1(12) DOTP1(13) DOTP1(14) DOTP1(15)
      REDUCE(a0) REDUCE(a1) REDUCE(a2) REDUCE(a3) REDUCE(a4) REDUCE(a5) REDUCE(a6) REDUCE(a7)
      {
        float sel = a0;
        sel = (ko==1)?a1:sel; sel = (ko==2)?a2:sel; sel = (ko==3)?a3:sel;
        sel = (ko==4)?a4:sel; sel = (ko==5)?a5:sel; sel = (ko==6)?a6:sel; sel = (ko==7)?a7:sel;
        float pre = sel + g1;
        float s = 1.f / (1.f + __expf(-pre));
        int o = no*8 + ko;
        if (no < 32){
          z_s[o] = s;
        } else {
          int op = o - 256;
          rHs16[op] = (f16)(s * hs32[op]);
        }
      }
      __syncthreads();

      // ---- phase 2
      uint32_t rp[16];
      {
        const uint2* rpp = (const uint2*)rHs16;
        #pragma unroll
        for (int j=0;j<8;j++){ uint2 v = rpp[ko*8 + j]; rp[2*j] = v.x; rp[2*j+1] = v.y; }
      }
      float b0=0.f,b1=0.f,b2=0.f,b3=0.f;
      DOTP2(0)  DOTP2(1)  DOTP2(2)  DOTP2(3)  DOTP2(4)  DOTP2(5)  DOTP2(6)  DOTP2(7)
      DOTP2(8)  DOTP2(9)  DOTP2(10) DOTP2(11) DOTP2(12) DOTP2(13) DOTP2(14) DOTP2(15)
      REDUCE(b0) REDUCE(b1) REDUCE(b2) REDUCE(b3)
      if (ko < 4){
        float sel = b0;
        sel = (ko==1)?b1:sel; sel = (ko==2)?b2:sel; sel = (ko==3)?b3:sel;
        int o = no*4 + ko;
        float pre = sel + g2;
        float ax = fabsf(pre);
        float e = __expf(2.f*ax);
        float th = 1.f - 2.f/(e + 1.f);      // tanh(|x|), safe at inf
        th = copysignf(th, pre);
        float z = z_s[o];
        float hn = z*th + (1.f - z)*hs32[o];
        hs32[o] = hn;
        ((f16*)hs16)[o] = (f16)hn;
        if (t == TT-1) hf_out[b*HH + o] = hn;
      }
      g1 = g1n; g2 = g2n;
      __syncthreads();
      // ---- release step t: 64 coalesced device-scope (sc1) stores of the H row,
      //      then wave-0 vmcnt drain + relaxed agent-scope increment. NO buffer_wbl2.
      if (tid < 64){
        u64 v = ((const u64*)hs16)[tid];
        __hip_atomic_store((u64*)(Hn16 + ((size_t)(t*BB + b) << 8)) + tid, v,
                           __ATOMIC_RELAXED, __HIP_MEMORY_SCOPE_AGENT);
      }
      if (tid == 0){
        asm volatile("s_waitcnt vmcnt(0)" ::: "memory");
        __hip_atomic_fetch_add(&ctl[t*32], 1, __ATOMIC_RELAXED, __HIP_MEMORY_SCOPE_AGENT);
      }
    }
  }

  // ================= consumer loop (all blocks; producers join for the tail) =========
  {
    const int lane = tid & 63, wid = tid >> 6;
    const int wm = wid & 1, wn = wid >> 1;       // 2M x 4N waves, each 64x64
    const int arow = tid >> 2, aseg = tid & 3;   // A: 128 rows x 4 seg (32 f16 each)
    const int brow = tid >> 1, bseg = tid & 1;   // B: 256 rows x 2 seg (64 f16 each)
    int fenced_t = -1;
    for (;;){
      if (tid == 0) sh_tile = atomicAdd(&ctl[4097], 1);
      __syncthreads();
      const int tile = sh_tile;
      if (tile >= NTILE) break;
      const int mg = tile / 125;
      const int ng = tile - mg*125;
      const int m0 = mg*128, n0 = ng*256;
      const int t_need = mg*4 + 3;
      if (tid == 0 && t_need > fenced_t){
        // passive poll: relaxed agent-scope LOAD (no RMW ownership), short sleep
        while (__hip_atomic_load(&ctl[t_need*32], __ATOMIC_RELAXED, __HIP_MEMORY_SCOPE_AGENT) < BB)
          __builtin_amdgcn_s_sleep(16);
        __threadfence();           // acquire: invalidate stale L1/L2 before reading Hn16
        fenced_t = t_need;
      }
      __syncthreads();

      f32x16 acc[2][2];
      {
        f32x16 z = {0.f};
        acc[0][0]=z; acc[0][1]=z; acc[1][0]=z; acc[1][1]=z;
      }

      #pragma unroll 1
      for (int kt=0; kt<2; kt++){
        {
          const uint4* asrc = (const uint4*)(Hn16 + (size_t)(m0+arow)*HH + kt*128 + aseg*32);
          #pragma unroll
          for (int j=0;j<4;j++){
            uint4 v = asrc[j];
            int byte = arow*256 + ((aseg*64 + j*16) ^ ((arow&15)<<4));
            *(uint4*)((char*)a_lds + byte) = v;
          }
          const uint4* bsrc = (const uint4*)(Wof + (size_t)(n0+brow)*HH + kt*128 + bseg*64);
          #pragma unroll
          for (int j=0;j<8;j++){
            uint4 v = bsrc[j];
            int byte = brow*256 + ((bseg*128 + j*16) ^ ((brow&15)<<4));
            *(uint4*)((char*)b_lds + byte) = v;
          }
        }
        __syncthreads();
        #pragma unroll
        for (int kk=0; kk<8; kk++){
          const int kbyte = kk*32 + (lane>>5)*16;
          f16x8 af[2], bf[2];
          #pragma unroll
          for (int mi=0;mi<2;mi++){
            int row = wm*64 + mi*32 + (lane&31);
            int byte = row*256 + (kbyte ^ ((row&15)<<4));
            af[mi] = *(const f16x8*)((const char*)a_lds + byte);
          }
          #pragma unroll
          for (int nj=0;nj<2;nj++){
            int nl = wn*64 + nj*32 + (lane&31);
            int byte = nl*256 + (kbyte ^ ((nl&15)<<4));
            bf[nj] = *(const f16x8*)((const char*)b_lds + byte);
          }
          #pragma unroll
          for (int mi=0;mi<2;mi++)
            #pragma unroll
            for (int nj=0;nj<2;nj++)
              acc[mi][nj] = __builtin_amdgcn_mfma_f32_32x32x16_f16(af[mi], bf[nj], acc[mi][nj], 0, 0, 0);
        }
        __syncthreads();
      }
      // epilogue: 32x32 C/D map (r15-validated): col=lane&31, row=(r&3)+8*(r>>2)+4*(lane>>5)
      #pragma unroll
      for (int nj=0;nj<2;nj++){
        const int col = n0 + wn*64 + nj*32 + (lane & 31);
        const float bov = bo[col];
        #pragma unroll
        for (int mi=0;mi<2;mi++){
          const int rbase = m0 + wm*64 + mi*32 + 4*(lane>>5);
          #pragma unroll
          for (int r=0;r<16;r++){
            int row = rbase + (r&3) + 8*(r>>2);
            Y[(size_t)row*VV + col] = acc[mi][nj][r] + bov;
          }
        }
      }
    }
  }
}

extern "C" void kernel_launch(void* const* d_in, const int* in_sizes, int n_in,
                              void* d_out, int out_size, void* d_ws, size_t ws_size,
                              hipStream_t stream){
  const int*   X  = (const int*)d_in[0];
  const float* H0 = (const float*)d_in[1];
  const float* Wz = (const float*)d_in[2];
  const float* bz = (const float*)d_in[3];
  const float* Wr = (const float*)d_in[4];
  const float* br = (const float*)d_in[5];
  const float* Wh = (const float*)d_in[6];
  const float* bh = (const float*)d_in[7];
  const float* Wo = (const float*)d_in[8];
  const float* bo = (const float*)d_in[9];
  float* out = (float*)d_out;

  char* ws = (char*)d_ws;
  int*      ctl   = (int*)ws;                       //     16,512 B (padded)
  uint32_t* Wpack = (uint32_t*)(ws + 16512);        //    393,216 B
  f16*      Hn16  = (f16*)(ws + 409728);            //  2,097,152 B
  f16*      Wof   = (f16*)(ws + 2506880);           // 16,384,000 B
  float*    g_buf = (float*)(ws + 18890880);        // 12,582,912 B

  k_init<<<5, 1024, 0, stream>>>(ctl);
  k_gather<<<4096, 256, 0, stream>>>(X, Wz, bz, Wr, br, Wh, bh, g_buf);
  k_pack<<<384, 256, 0, stream>>>(Wz, Wr, Wh, Wpack);
  k_wo<<<4000, 256, 0, stream>>>(Wo, Wof);
  k_main<<<256, 512, 0, stream>>>(H0, Wpack, g_buf, Wof, bo, Hn16, out, out + 131072000LL, ctl);
}

// Round 19
// 476.040 us; speedup vs baseline: 2.3294x; 1.1215x over previous
//
#include <hip/hip_runtime.h>
#include <hip/hip_fp16.h>
#include <stdint.h>

#define VV 32000
#define HH 256
#define BB 32
#define TT 128
#define VH 32256   // V + H
#define NTILE 4000 // 32 m-groups x 125 n-tiles(256)

typedef _Float16 f16;
typedef _Float16 f16x2 __attribute__((ext_vector_type(2)));
typedef _Float16 f16x8 __attribute__((ext_vector_type(8)));
typedef float f32x16 __attribute__((ext_vector_type(16)));
typedef unsigned long long u64;

static __device__ __forceinline__ float dot2f(uint32_t w, uint32_t h, float acc){
  f16x2 a = __builtin_bit_cast(f16x2, w);
  f16x2 b = __builtin_bit_cast(f16x2, h);
#if __has_builtin(__builtin_amdgcn_fdot2)
  return __builtin_amdgcn_fdot2(a, b, acc, false);
#else
  acc = fmaf((float)a[0], (float)b[0], acc);
  acc = fmaf((float)a[1], (float)b[1], acc);
  return acc;
#endif
}

// ---------------- merged prologue: gather (0..4095) | pack (4096..4479) | wo (4480..8479) | init (8480)
__global__ void k_prep(const int* __restrict__ X,
                       const float* __restrict__ Wz, const float* __restrict__ bz,
                       const float* __restrict__ Wr, const float* __restrict__ br,
                       const float* __restrict__ Wh, const float* __restrict__ bh,
                       const float* __restrict__ Wo,
                       float* __restrict__ g_buf, uint32_t* __restrict__ Wpack,
                       f16* __restrict__ Wof, int* __restrict__ ctl){
  const int bid = blockIdx.x;
  const int tidx = threadIdx.x;
  if (bid < 4096){
    // gather: g[t*32+b][o] = W_gate[row][tok] + bias  (coalesced output)
    int t = bid >> 5, b = bid & 31;
    int tok = X[b*TT + t];
    int o = tidx;
    g_buf[(size_t)bid*768 + o]       = Wz[(size_t)o*VH + tok] + bz[o];
    g_buf[(size_t)bid*768 + 256 + o] = Wr[(size_t)o*VH + tok] + br[o];
    g_buf[(size_t)bid*768 + 512 + o] = Wh[(size_t)o*VH + tok] + bh[o];
  } else if (bid < 4480){
    // pack recurrent weights (512-thread producer layout, round-8 mapping)
    int idx = (bid - 4096)*256 + tidx;
    if (idx < 512*192){
      int t = idx / 192, rem = idx - t*192;
      int ol = rem >> 4, p = rem & 15;
      int ko = t & 7, no = t >> 3;
      int k = ko*32 + p*2;
      const float* W; int row;
      if (ol < 8){ int o = no*8 + ol; if (o < 256){ W = Wz; row = o; } else { W = Wr; row = o - 256; } }
      else { W = Wh; row = no*4 + (ol - 8); }
      float a = W[(size_t)row*VH + VV + k];
      float c = W[(size_t)row*VH + VV + k + 1];
      f16x2 v; v[0] = (f16)a; v[1] = (f16)c;
      Wpack[idx] = __builtin_bit_cast(uint32_t, v);
    }
  } else if (bid < 8480){
    // Wo f32 -> f16
    int i = (bid - 4480)*256 + tidx;
    const float4* s = (const float4*)Wo + (size_t)i*2;
    float4 f0 = s[0], f1 = s[1];
    f16x8 h;
    h[0]=(f16)f0.x; h[1]=(f16)f0.y; h[2]=(f16)f0.z; h[3]=(f16)f0.w;
    h[4]=(f16)f1.x; h[5]=(f16)f1.y; h[6]=(f16)f1.z; h[7]=(f16)f1.w;
    *(f16x8*)(Wof + (size_t)i*8) = h;
  } else {
    // ctl init
    for (int i = tidx; i < 4100; i += 256) ctl[i] = 0;
  }
}

// ==== AGPR machinery (r13-validated): weights pinned in AGPRs, volatile reads per use ====
#define DECL16(P) uint32_t P##_0,P##_1,P##_2,P##_3,P##_4,P##_5,P##_6,P##_7, \
                           P##_8,P##_9,P##_10,P##_11,P##_12,P##_13,P##_14,P##_15;
#define LDQ(j,e0,e1,e2,e3) { uint4 v_ = src[j]; \
  asm("v_accvgpr_write_b32 %0, %1" : "=a"(e0) : "v"(v_.x)); \
  asm("v_accvgpr_write_b32 %0, %1" : "=a"(e1) : "v"(v_.y)); \
  asm("v_accvgpr_write_b32 %0, %1" : "=a"(e2) : "v"(v_.z)); \
  asm("v_accvgpr_write_b32 %0, %1" : "=a"(e3) : "v"(v_.w)); }
#define LDROW(r,P) LDQ(4*(r)+0,P##_0,P##_1,P##_2,P##_3)   LDQ(4*(r)+1,P##_4,P##_5,P##_6,P##_7) \
                   LDQ(4*(r)+2,P##_8,P##_9,P##_10,P##_11) LDQ(4*(r)+3,P##_12,P##_13,P##_14,P##_15)
#define RD(a_) __extension__({ uint32_t t_; \
  asm volatile("v_accvgpr_read_b32 %0, %1" : "=v"(t_) : "a"(a_)); t_; })
#define DOTP1(p) \
  a0 = dot2f(RD(w0_##p), hp[p], a0);  a1 = dot2f(RD(w1_##p), hp[p], a1); \
  a2 = dot2f(RD(w2_##p), hp[p], a2);  a3 = dot2f(RD(w3_##p), hp[p], a3); \
  a4 = dot2f(RD(w4_##p), hp[p], a4);  a5 = dot2f(RD(w5_##p), hp[p], a5); \
  a6 = dot2f(RD(w6_##p), hp[p], a6);  a7 = dot2f(RD(w7_##p), hp[p], a7);
#define DOTP2(p) \
  b0 = dot2f(RD(w8_##p),  rp[p], b0); b1 = dot2f(RD(w9_##p),  rp[p], b1); \
  b2 = dot2f(RD(w10_##p), rp[p], b2); b3 = dot2f(RD(w11_##p), rp[p], b3);
#define REDUCE(x) x += __shfl_xor(x,1); x += __shfl_xor(x,2); x += __shfl_xor(x,4);

// ---------------- fused: 256 blocks x 512 thr (1 block/CU). First 32 arrivals: producer.
__global__ __launch_bounds__(512)
__attribute__((amdgpu_waves_per_eu(2, 2)))
void k_main(const float* __restrict__ H0, const uint32_t* __restrict__ Wpack,
            const float* __restrict__ g_buf,
            const f16* __restrict__ Wof, const float* __restrict__ bo,
            f16* __restrict__ Hn16, float* __restrict__ Y, float* __restrict__ hf_out,
            int* __restrict__ ctl){
  __shared__ __align__(16) f16 a_lds[128*128];     // 32 KB (consumer A)
  __shared__ __align__(16) f16 b_lds[256*128];     // 64 KB (consumer B)
  __shared__ __align__(16) uint32_t hs16[128];
  __shared__ __align__(16) f16 rHs16[256];
  __shared__ __align__(16) u64 hstage[256];        // 2 KB: 4 batched H rows (f16)
  __shared__ float hs32[256];
  __shared__ float z_s[256];
  __shared__ int sh_role, sh_tile;
  const int tid = threadIdx.x;
  if (tid == 0) sh_role = atomicAdd(&ctl[4096], 1);
  __syncthreads();
  const int role = sh_role;

  if (role < BB){
    // ================= producer: recurrence for batch b (explicit-AGPR + g_buf) =======
    const int b = role;
    const int ko = tid & 7, no = tid >> 3;

    DECL16(w0) DECL16(w1) DECL16(w2)  DECL16(w3)  DECL16(w4)  DECL16(w5)
    DECL16(w6) DECL16(w7) DECL16(w8)  DECL16(w9)  DECL16(w10) DECL16(w11)
    {
      const uint4* src = (const uint4*)(Wpack + (size_t)tid*192);
      LDROW(0,w0) LDROW(1,w1) LDROW(2,w2)   LDROW(3,w3)  LDROW(4,w4)  LDROW(5,w5)
      LDROW(6,w6) LDROW(7,w7) LDROW(8,w8)   LDROW(9,w9)  LDROW(10,w10) LDROW(11,w11)
    }

    if (tid < 256) hs32[tid] = H0[b*HH + tid];
    __syncthreads();
    if (tid < 128){
      f16x2 v; v[0] = (f16)hs32[2*tid]; v[1] = (f16)hs32[2*tid+1];
      hs16[tid] = __builtin_bit_cast(uint32_t, v);
    }
    __syncthreads();

    const int gi1 = no*8 + ko;
    const int gi2 = 512 + no*4 + (ko & 3);
    float g1 = g_buf[(size_t)b*768 + gi1];
    float g2 = g_buf[(size_t)b*768 + gi2];
    float g1n = 0.f, g2n = 0.f;

    for (int t = 0; t < TT; t++){
      if (t < TT-1){
        const float* gn = g_buf + (size_t)((t+1)*BB + b)*768;
        g1n = gn[gi1];
        g2n = gn[gi2];
      }

      // ---- phase 1: z (no<32) and r (no>=32), 8 outputs per group
      uint32_t hp[16];
      {
        const uint2* hsp = (const uint2*)hs16;
        #pragma unroll
        for (int j=0;j<8;j++){ uint2 v = hsp[ko*8 + j]; hp[2*j] = v.x; hp[2*j+1] = v.y; }
      }
      float a0=0.f,a1=0.f,a2=0.f,a3=0.f,a4=0.f,a5=0.f,a6=0.f,a7=0.f;
      DOTP1(0)  DOTP1(1)  DOTP1(2)  DOTP1(3)  DOTP1(4)  DOTP1(5)  DOTP1(6)  DOTP1(7)
      DOTP1(8)  DOTP1(9)  DOTP1(10) DOTP1(11) DOTP1(12) DOTP1(13) DOTP1(14) DOTP1(15)
      REDUCE(a0) REDUCE(a1) REDUCE(a2) REDUCE(a3) REDUCE(a4) REDUCE(a5) REDUCE(a6) REDUCE(a7)
      {
        float sel = a0;
        sel = (ko==1)?a1:sel; sel = (ko==2)?a2:sel; sel = (ko==3)?a3:sel;
        sel = (ko==4)?a4:sel; sel = (ko==5)?a5:sel; sel = (ko==6)?a6:sel; sel = (ko==7)?a7:sel;
        float pre = sel + g1;
        float s = 1.f / (1.f + __expf(-pre));
        int o = no*8 + ko;
        if (no < 32){
          z_s[o] = s;
        } else {
          int op = o - 256;
          rHs16[op] = (f16)(s * hs32[op]);
        }
      }
      __syncthreads();

      // ---- phase 2
      uint32_t rp[16];
      {
        const uint2* rpp = (const uint2*)rHs16;
        #pragma unroll
        for (int j=0;j<8;j++){ uint2 v = rpp[ko*8 + j]; rp[2*j] = v.x; rp[2*j+1] = v.y; }
      }
      float b0=0.f,b1=0.f,b2=0.f,b3=0.f;
      DOTP2(0)  DOTP2(1)  DOTP2(2)  DOTP2(3)  DOTP2(4)  DOTP2(5)  DOTP2(6)  DOTP2(7)
      DOTP2(8)  DOTP2(9)  DOTP2(10) DOTP2(11) DOTP2(12) DOTP2(13) DOTP2(14) DOTP2(15)
      REDUCE(b0) REDUCE(b1) REDUCE(b2) REDUCE(b3)
      if (ko < 4){
        float sel = b0;
        sel = (ko==1)?b1:sel; sel = (ko==2)?b2:sel; sel = (ko==3)?b3:sel;
        int o = no*4 + ko;
        float pre = sel + g2;
        float ax = fabsf(pre);
        float e = __expf(2.f*ax);
        float th = 1.f - 2.f/(e + 1.f);      // tanh(|x|), safe at inf
        th = copysignf(th, pre);
        float z = z_s[o];
        float hn = z*th + (1.f - z)*hs32[o];
        hs32[o] = hn;
        ((f16*)hs16)[o] = (f16)hn;
        ((f16*)hstage)[(t&3)*256 + o] = (f16)hn;   // batch-release staging
        if (t == TT-1) hf_out[b*HH + o] = hn;
      }
      g1 = g1n; g2 = g2n;
      __syncthreads();
      // ---- batched release every 4 steps: 256 coalesced sc1 u64 stores (rows t-3..t),
      //      barrier (drains vmcnt for all waves), then one relaxed agent-scope increment.
      if ((t & 3) == 3){
        if (tid < 256){
          int s = tid >> 6, lane = tid & 63;
          int tr = t - 3 + s;
          u64 v = hstage[tid];
          __hip_atomic_store(((u64*)Hn16) + (((size_t)(tr*BB + b)) << 6) + lane, v,
                             __ATOMIC_RELAXED, __HIP_MEMORY_SCOPE_AGENT);
        }
        __syncthreads();
        if (tid == 0)
          __hip_atomic_fetch_add(&ctl[t*32], 1, __ATOMIC_RELAXED, __HIP_MEMORY_SCOPE_AGENT);
      }
    }
  }

  // ================= consumer loop (all blocks; producers join for the tail) =========
  {
    const int lane = tid & 63, wid = tid >> 6;
    const int wm = wid & 1, wn = wid >> 1;       // 2M x 4N waves, each 64x64
    const int arow = tid >> 2, aseg = tid & 3;   // A: 128 rows x 4 seg (32 f16 each)
    const int brow = tid >> 1, bseg = tid & 1;   // B: 256 rows x 2 seg (64 f16 each)
    int fenced_t = -1;
    for (;;){
      if (tid == 0) sh_tile = atomicAdd(&ctl[4097], 1);
      __syncthreads();
      const int tile = sh_tile;
      if (tile >= NTILE) break;
      const int mg = tile / 125;
      const int ng = tile - mg*125;
      const int m0 = mg*128, n0 = ng*256;
      const int t_need = mg*4 + 3;
      if (tid == 0 && t_need > fenced_t){
        while (__hip_atomic_load(&ctl[t_need*32], __ATOMIC_RELAXED, __HIP_MEMORY_SCOPE_AGENT) < BB)
          __builtin_amdgcn_s_sleep(16);
        __threadfence();           // acquire: invalidate stale L1/L2 before reading Hn16
        fenced_t = t_need;
      }
      __syncthreads();

      f32x16 acc[2][2];
      {
        f32x16 z = {0.f};
        acc[0][0]=z; acc[0][1]=z; acc[1][0]=z; acc[1][1]=z;
      }

      #pragma unroll 1
      for (int kt=0; kt<2; kt++){
        {
          const uint4* asrc = (const uint4*)(Hn16 + (size_t)(m0+arow)*HH + kt*128 + aseg*32);
          #pragma unroll
          for (int j=0;j<4;j++){
            uint4 v = asrc[j];
            int byte = arow*256 + ((aseg*64 + j*16) ^ ((arow&15)<<4));
            *(uint4*)((char*)a_lds + byte) = v;
          }
          const uint4* bsrc = (const uint4*)(Wof + (size_t)(n0+brow)*HH + kt*128 + bseg*64);
          #pragma unroll
          for (int j=0;j<8;j++){
            uint4 v = bsrc[j];
            int byte = brow*256 + ((bseg*128 + j*16) ^ ((brow&15)<<4));
            *(uint4*)((char*)b_lds + byte) = v;
          }
        }
        __syncthreads();
        #pragma unroll
        for (int kk=0; kk<8; kk++){
          const int kbyte = kk*32 + (lane>>5)*16;
          f16x8 af[2], bf[2];
          #pragma unroll
          for (int mi=0;mi<2;mi++){
            int row = wm*64 + mi*32 + (lane&31);
            int byte = row*256 + (kbyte ^ ((row&15)<<4));
            af[mi] = *(const f16x8*)((const char*)a_lds + byte);
          }
          #pragma unroll
          for (int nj=0;nj<2;nj++){
            int nl = wn*64 + nj*32 + (lane&31);
            int byte = nl*256 + (kbyte ^ ((nl&15)<<4));
            bf[nj] = *(const f16x8*)((const char*)b_lds + byte);
          }
          #pragma unroll
          for (int mi=0;mi<2;mi++)
            #pragma unroll
            for (int nj=0;nj<2;nj++)
              acc[mi][nj] = __builtin_amdgcn_mfma_f32_32x32x16_f16(af[mi], bf[nj], acc[mi][nj], 0, 0, 0);
        }
        __syncthreads();
      }
      // epilogue: 32x32 C/D map (r15-validated): col=lane&31, row=(r&3)+8*(r>>2)+4*(lane>>5)
      #pragma unroll
      for (int nj=0;nj<2;nj++){
        const int col = n0 + wn*64 + nj*32 + (lane & 31);
        const float bov = bo[col];
        #pragma unroll
        for (int mi=0;mi<2;mi++){
          const int rbase = m0 + wm*64 + mi*32 + 4*(lane>>5);
          #pragma unroll
          for (int r=0;r<16;r++){
            int row = rbase + (r&3) + 8*(r>>2);
            Y[(size_t)row*VV + col] = acc[mi][nj][r] + bov;
          }
        }
      }
    }
  }
}

extern "C" void kernel_launch(void* const* d_in, const int* in_sizes, int n_in,
                              void* d_out, int out_size, void* d_ws, size_t ws_size,
                              hipStream_t stream){
  const int*   X  = (const int*)d_in[0];
  const float* H0 = (const float*)d_in[1];
  const float* Wz = (const float*)d_in[2];
  const float* bz = (const float*)d_in[3];
  const float* Wr = (const float*)d_in[4];
  const float* br = (const float*)d_in[5];
  const float* Wh = (const float*)d_in[6];
  const float* bh = (const float*)d_in[7];
  const float* Wo = (const float*)d_in[8];
  const float* bo = (const float*)d_in[9];
  float* out = (float*)d_out;

  char* ws = (char*)d_ws;
  int*      ctl   = (int*)ws;                       //     16,512 B (padded)
  uint32_t* Wpack = (uint32_t*)(ws + 16512);        //    393,216 B
  f16*      Hn16  = (f16*)(ws + 409728);            //  2,097,152 B
  f16*      Wof   = (f16*)(ws + 2506880);           // 16,384,000 B
  float*    g_buf = (float*)(ws + 18890880);        // 12,582,912 B

  k_prep<<<8481, 256, 0, stream>>>(X, Wz, bz, Wr, br, Wh, bh, Wo, g_buf, Wpack, Wof, ctl);
  k_main<<<256, 512, 0, stream>>>(H0, Wpack, g_buf, Wof, bo, Hn16, out, out + 131072000LL, ctl);
}

// Round 20
// 458.240 us; speedup vs baseline: 2.4199x; 1.0388x over previous
//
#include <hip/hip_runtime.h>
#include <hip/hip_fp16.h>
#include <stdint.h>

#define VV 32000
#define HH 256
#define BB 32
#define TT 128
#define VH 32256   // V + H
#define NTILE 4000 // 32 m-groups x 125 n-tiles(256)

typedef _Float16 f16;
typedef _Float16 f16x2 __attribute__((ext_vector_type(2)));
typedef _Float16 f16x8 __attribute__((ext_vector_type(8)));
typedef float f32x16 __attribute__((ext_vector_type(16)));
typedef unsigned long long u64;

static __device__ __forceinline__ float dot2f(uint32_t w, uint32_t h, float acc){
  f16x2 a = __builtin_bit_cast(f16x2, w);
  f16x2 b = __builtin_bit_cast(f16x2, h);
#if __has_builtin(__builtin_amdgcn_fdot2)
  return __builtin_amdgcn_fdot2(a, b, acc, false);
#else
  acc = fmaf((float)a[0], (float)b[0], acc);
  acc = fmaf((float)a[1], (float)b[1], acc);
  return acc;
#endif
}

// ---------------- merged prologue: gather (0..4095) | pack (4096..4479) | wo (4480..8479) | init (8480)
__global__ void k_prep(const int* __restrict__ X,
                       const float* __restrict__ Wz, const float* __restrict__ bz,
                       const float* __restrict__ Wr, const float* __restrict__ br,
                       const float* __restrict__ Wh, const float* __restrict__ bh,
                       const float* __restrict__ Wo,
                       float* __restrict__ g_buf, uint32_t* __restrict__ Wpack,
                       f16* __restrict__ Wof, int* __restrict__ ctl){
  const int bid = blockIdx.x;
  const int tidx = threadIdx.x;
  if (bid < 4096){
    int t = bid >> 5, b = bid & 31;
    int tok = X[b*TT + t];
    int o = tidx;
    g_buf[(size_t)bid*768 + o]       = Wz[(size_t)o*VH + tok] + bz[o];
    g_buf[(size_t)bid*768 + 256 + o] = Wr[(size_t)o*VH + tok] + br[o];
    g_buf[(size_t)bid*768 + 512 + o] = Wh[(size_t)o*VH + tok] + bh[o];
  } else if (bid < 4480){
    int idx = (bid - 4096)*256 + tidx;
    if (idx < 512*192){
      int t = idx / 192, rem = idx - t*192;
      int ol = rem >> 4, p = rem & 15;
      int ko = t & 7, no = t >> 3;
      int k = ko*32 + p*2;
      const float* W; int row;
      if (ol < 8){ int o = no*8 + ol; if (o < 256){ W = Wz; row = o; } else { W = Wr; row = o - 256; } }
      else { W = Wh; row = no*4 + (ol - 8); }
      float a = W[(size_t)row*VH + VV + k];
      float c = W[(size_t)row*VH + VV + k + 1];
      f16x2 v; v[0] = (f16)a; v[1] = (f16)c;
      Wpack[idx] = __builtin_bit_cast(uint32_t, v);
    }
  } else if (bid < 8480){
    int i = (bid - 4480)*256 + tidx;
    const float4* s = (const float4*)Wo + (size_t)i*2;
    float4 f0 = s[0], f1 = s[1];
    f16x8 h;
    h[0]=(f16)f0.x; h[1]=(f16)f0.y; h[2]=(f16)f0.z; h[3]=(f16)f0.w;
    h[4]=(f16)f1.x; h[5]=(f16)f1.y; h[6]=(f16)f1.z; h[7]=(f16)f1.w;
    *(f16x8*)(Wof + (size_t)i*8) = h;
  } else {
    for (int i = tidx; i < 4100; i += 256) ctl[i] = 0;
  }
}

// ==== AGPR machinery: weights pinned in AGPRs; reads batched 8-ahead to hide RAW latency ====
#define DECL16(P) uint32_t P##_0,P##_1,P##_2,P##_3,P##_4,P##_5,P##_6,P##_7, \
                           P##_8,P##_9,P##_10,P##_11,P##_12,P##_13,P##_14,P##_15;
#define LDQ(j,e0,e1,e2,e3) { uint4 v_ = src[j]; \
  asm("v_accvgpr_write_b32 %0, %1" : "=a"(e0) : "v"(v_.x)); \
  asm("v_accvgpr_write_b32 %0, %1" : "=a"(e1) : "v"(v_.y)); \
  asm("v_accvgpr_write_b32 %0, %1" : "=a"(e2) : "v"(v_.z)); \
  asm("v_accvgpr_write_b32 %0, %1" : "=a"(e3) : "v"(v_.w)); }
#define LDROW(r,P) LDQ(4*(r)+0,P##_0,P##_1,P##_2,P##_3)   LDQ(4*(r)+1,P##_4,P##_5,P##_6,P##_7) \
                   LDQ(4*(r)+2,P##_8,P##_9,P##_10,P##_11) LDQ(4*(r)+3,P##_12,P##_13,P##_14,P##_15)
#define RD(a_) __extension__({ uint32_t t_; \
  asm volatile("v_accvgpr_read_b32 %0, %1" : "=v"(t_) : "a"(a_)); t_; })
// batched: issue all 8 AGPR reads, THEN the 8 dot2s (no back-to-back RAW stalls)
#define DOTP1(p) { \
  uint32_t r0_=RD(w0_##p), r1_=RD(w1_##p), r2_=RD(w2_##p), r3_=RD(w3_##p), \
           r4_=RD(w4_##p), r5_=RD(w5_##p), r6_=RD(w6_##p), r7_=RD(w7_##p); \
  a0 = dot2f(r0_, hp[p], a0); a1 = dot2f(r1_, hp[p], a1); \
  a2 = dot2f(r2_, hp[p], a2); a3 = dot2f(r3_, hp[p], a3); \
  a4 = dot2f(r4_, hp[p], a4); a5 = dot2f(r5_, hp[p], a5); \
  a6 = dot2f(r6_, hp[p], a6); a7 = dot2f(r7_, hp[p], a7); }
#define DOTP2(p) { \
  uint32_t r8_=RD(w8_##p), r9_=RD(w9_##p), r10_=RD(w10_##p), r11_=RD(w11_##p); \
  b0 = dot2f(r8_,  rp[p], b0); b1 = dot2f(r9_,  rp[p], b1); \
  b2 = dot2f(r10_, rp[p], b2); b3 = dot2f(r11_, rp[p], b3); }
#define REDUCE(x) x += __shfl_xor(x,1); x += __shfl_xor(x,2); x += __shfl_xor(x,4);

// ---------------- fused: 256 blocks x 512 thr (1 block/CU). First 32 arrivals: producer.
__global__ __launch_bounds__(512)
__attribute__((amdgpu_waves_per_eu(2, 2)))
void k_main(const float* __restrict__ H0, const uint32_t* __restrict__ Wpack,
            const float* __restrict__ g_buf,
            const f16* __restrict__ Wof, const float* __restrict__ bo,
            f16* __restrict__ Hn16, float* __restrict__ Y, float* __restrict__ hf_out,
            int* __restrict__ ctl){
  __shared__ __align__(16) f16 a_lds[128*128];     // 32 KB (consumer A)
  __shared__ __align__(16) f16 b_lds[256*128];     // 64 KB (consumer B)
  __shared__ __align__(16) uint32_t hs16[128];
  __shared__ __align__(16) f16 rHs16[256];
  __shared__ __align__(16) u64 hstage[256];        // 2 KB: 4 batched H rows (f16)
  __shared__ float hs32[256];
  __shared__ float z_s[256];
  __shared__ int sh_role, sh_tile;
  const int tid = threadIdx.x;
  if (tid == 0) sh_role = atomicAdd(&ctl[4096], 1);
  __syncthreads();
  const int role = sh_role;

  if (role < BB){
    // ================= producer: recurrence for batch b (explicit-AGPR + g_buf) =======
    const int b = role;
    const int ko = tid & 7, no = tid >> 3;

    DECL16(w0) DECL16(w1) DECL16(w2)  DECL16(w3)  DECL16(w4)  DECL16(w5)
    DECL16(w6) DECL16(w7) DECL16(w8)  DECL16(w9)  DECL16(w10) DECL16(w11)
    {
      const uint4* src = (const uint4*)(Wpack + (size_t)tid*192);
      LDROW(0,w0) LDROW(1,w1) LDROW(2,w2)   LDROW(3,w3)  LDROW(4,w4)  LDROW(5,w5)
      LDROW(6,w6) LDROW(7,w7) LDROW(8,w8)   LDROW(9,w9)  LDROW(10,w10) LDROW(11,w11)
    }

    if (tid < 256) hs32[tid] = H0[b*HH + tid];
    __syncthreads();
    if (tid < 128){
      f16x2 v; v[0] = (f16)hs32[2*tid]; v[1] = (f16)hs32[2*tid+1];
      hs16[tid] = __builtin_bit_cast(uint32_t, v);
    }
    __syncthreads();

    const int gi1 = no*8 + ko;
    const int gi2 = 512 + no*4 + (ko & 3);
    float g1 = g_buf[(size_t)b*768 + gi1];
    float g2 = g_buf[(size_t)b*768 + gi2];
    float g1n = 0.f, g2n = 0.f;

    for (int t = 0; t < TT; t++){
      if (t < TT-1){
        const float* gn = g_buf + (size_t)((t+1)*BB + b)*768;
        g1n = gn[gi1];
        g2n = gn[gi2];
      }

      // ---- phase 1: z (no<32) and r (no>=32), 8 outputs per group
      uint32_t hp[16];
      {
        const uint2* hsp = (const uint2*)hs16;
        #pragma unroll
        for (int j=0;j<8;j++){ uint2 v = hsp[ko*8 + j]; hp[2*j] = v.x; hp[2*j+1] = v.y; }
      }
      float a0=0.f,a1=0.f,a2=0.f,a3=0.f,a4=0.f,a5=0.f,a6=0.f,a7=0.f;
      DOTP1(0)  DOTP1(1)  DOTP1(2)  DOTP1(3)  DOTP1(4)  DOTP1(5)  DOTP1(6)  DOTP1(7)
      DOTP1(8)  DOTP1(9)  DOTP1(10) DOTP1(11) DOTP1(12) DOTP1(13) DOTP1(14) DOTP1(15)
      REDUCE(a0) REDUCE(a1) REDUCE(a2) REDUCE(a3) REDUCE(a4) REDUCE(a5) REDUCE(a6) REDUCE(a7)
      {
        float sel = a0;
        sel = (ko==1)?a1:sel; sel = (ko==2)?a2:sel; sel = (ko==3)?a3:sel;
        sel = (ko==4)?a4:sel; sel = (ko==5)?a5:sel; sel = (ko==6)?a6:sel; sel = (ko==7)?a7:sel;
        float pre = sel + g1;
        float s = 1.f / (1.f + __expf(-pre));
        int o = no*8 + ko;
        if (no < 32){
          z_s[o] = s;
        } else {
          int op = o - 256;
          rHs16[op] = (f16)(s * hs32[op]);
        }
      }
      __syncthreads();

      // ---- phase 2
      uint32_t rp[16];
      {
        const uint2* rpp = (const uint2*)rHs16;
        #pragma unroll
        for (int j=0;j<8;j++){ uint2 v = rpp[ko*8 + j]; rp[2*j] = v.x; rp[2*j+1] = v.y; }
      }
      float b0=0.f,b1=0.f,b2=0.f,b3=0.f;
      DOTP2(0)  DOTP2(1)  DOTP2(2)  DOTP2(3)  DOTP2(4)  DOTP2(5)  DOTP2(6)  DOTP2(7)
      DOTP2(8)  DOTP2(9)  DOTP2(10) DOTP2(11) DOTP2(12) DOTP2(13) DOTP2(14) DOTP2(15)
      REDUCE(b0) REDUCE(b1) REDUCE(b2) REDUCE(b3)
      if (ko < 4){
        float sel = b0;
        sel = (ko==1)?b1:sel; sel = (ko==2)?b2:sel; sel = (ko==3)?b3:sel;
        int o = no*4 + ko;
        float pre = sel + g2;
        float ax = fabsf(pre);
        float e = __expf(2.f*ax);
        float th = 1.f - 2.f/(e + 1.f);      // tanh(|x|), safe at inf
        th = copysignf(th, pre);
        float z = z_s[o];
        float hn = z*th + (1.f - z)*hs32[o];
        hs32[o] = hn;
        ((f16*)hs16)[o] = (f16)hn;
        ((f16*)hstage)[(t&3)*256 + o] = (f16)hn;   // batch-release staging
        if (t == TT-1) hf_out[b*HH + o] = hn;
      }
      g1 = g1n; g2 = g2n;
      __syncthreads();
      // ---- batched release every 4 steps: 256 coalesced sc1 u64 stores (rows t-3..t),
      //      barrier (drains vmcnt for all waves), then one relaxed agent-scope increment.
      if ((t & 3) == 3){
        if (tid < 256){
          int s = tid >> 6, lane = tid & 63;
          int tr = t - 3 + s;
          u64 v = hstage[tid];
          __hip_atomic_store(((u64*)Hn16) + (((size_t)(tr*BB + b)) << 6) + lane, v,
                             __ATOMIC_RELAXED, __HIP_MEMORY_SCOPE_AGENT);
        }
        __syncthreads();
        if (tid == 0)
          __hip_atomic_fetch_add(&ctl[t*32], 1, __ATOMIC_RELAXED, __HIP_MEMORY_SCOPE_AGENT);
      }
    }
  }

  // ================= consumer loop (all blocks; producers join for the tail) =========
  {
    const int lane = tid & 63, wid = tid >> 6;
    const int wm = wid & 1, wn = wid >> 1;       // 2M x 4N waves, each 64x64
    const int arow = tid >> 2, aseg = tid & 3;   // A: 128 rows x 4 seg (32 f16 each)
    const int brow = tid >> 1, bseg = tid & 1;   // B: 256 rows x 2 seg (64 f16 each)
    int fenced_t = -1;
    for (;;){
      if (tid == 0) sh_tile = atomicAdd(&ctl[4097], 1);
      __syncthreads();
      const int tile = sh_tile;
      if (tile >= NTILE) break;
      const int mg = tile / 125;
      const int ng = tile - mg*125;
      const int m0 = mg*128, n0 = ng*256;
      const int t_need = mg*4 + 3;
      if (tid == 0 && t_need > fenced_t){
        while (__hip_atomic_load(&ctl[t_need*32], __ATOMIC_RELAXED, __HIP_MEMORY_SCOPE_AGENT) < BB)
          __builtin_amdgcn_s_sleep(16);
        __threadfence();           // acquire: invalidate stale L1/L2 before reading Hn16
        fenced_t = t_need;
      }
      __syncthreads();

      f32x16 acc[2][2];
      {
        f32x16 z = {0.f};
        acc[0][0]=z; acc[0][1]=z; acc[1][0]=z; acc[1][1]=z;
      }

      #pragma unroll 1
      for (int kt=0; kt<2; kt++){
        {
          const uint4* asrc = (const uint4*)(Hn16 + (size_t)(m0+arow)*HH + kt*128 + aseg*32);
          #pragma unroll
          for (int j=0;j<4;j++){
            uint4 v = asrc[j];
            int byte = arow*256 + ((aseg*64 + j*16) ^ ((arow&15)<<4));
            *(uint4*)((char*)a_lds + byte) = v;
          }
          const uint4* bsrc = (const uint4*)(Wof + (size_t)(n0+brow)*HH + kt*128 + bseg*64);
          #pragma unroll
          for (int j=0;j<8;j++){
            uint4 v = bsrc[j];
            int byte = brow*256 + ((bseg*128 + j*16) ^ ((brow&15)<<4));
            *(uint4*)((char*)b_lds + byte) = v;
          }
        }
        __syncthreads();
        #pragma unroll
        for (int kk=0; kk<8; kk++){
          const int kbyte = kk*32 + (lane>>5)*16;
          f16x8 af[2], bf[2];
          #pragma unroll
          for (int mi=0;mi<2;mi++){
            int row = wm*64 + mi*32 + (lane&31);
            int byte = row*256 + (kbyte ^ ((row&15)<<4));
            af[mi] = *(const f16x8*)((const char*)a_lds + byte);
          }
          #pragma unroll
          for (int nj=0;nj<2;nj++){
            int nl = wn*64 + nj*32 + (lane&31);
            int byte = nl*256 + (kbyte ^ ((nl&15)<<4));
            bf[nj] = *(const f16x8*)((const char*)b_lds + byte);
          }
          #pragma unroll
          for (int mi=0;mi<2;mi++)
            #pragma unroll
            for (int nj=0;nj<2;nj++)
              acc[mi][nj] = __builtin_amdgcn_mfma_f32_32x32x16_f16(af[mi], bf[nj], acc[mi][nj], 0, 0, 0);
        }
        __syncthreads();
      }
      // epilogue: 32x32 C/D map (r15-validated): col=lane&31, row=(r&3)+8*(r>>2)+4*(lane>>5)
      #pragma unroll
      for (int nj=0;nj<2;nj++){
        const int col = n0 + wn*64 + nj*32 + (lane & 31);
        const float bov = bo[col];
        #pragma unroll
        for (int mi=0;mi<2;mi++){
          const int rbase = m0 + wm*64 + mi*32 + 4*(lane>>5);
          #pragma unroll
          for (int r=0;r<16;r++){
            int row = rbase + (r&3) + 8*(r>>2);
            Y[(size_t)row*VV + col] = acc[mi][nj][r] + bov;
          }
        }
      }
    }
  }
}

extern "C" void kernel_launch(void* const* d_in, const int* in_sizes, int n_in,
                              void* d_out, int out_size, void* d_ws, size_t ws_size,
                              hipStream_t stream){
  const int*   X  = (const int*)d_in[0];
  const float* H0 = (const float*)d_in[1];
  const float* Wz = (const float*)d_in[2];
  const float* bz = (const float*)d_in[3];
  const float* Wr = (const float*)d_in[4];
  const float* br = (const float*)d_in[5];
  const float* Wh = (const float*)d_in[6];
  const float* bh = (const float*)d_in[7];
  const float* Wo = (const float*)d_in[8];
  const float* bo = (const float*)d_in[9];
  float* out = (float*)d_out;

  char* ws = (char*)d_ws;
  int*      ctl   = (int*)ws;                       //     16,512 B (padded)
  uint32_t* Wpack = (uint32_t*)(ws + 16512);        //    393,216 B
  f16*      Hn16  = (f16*)(ws + 409728);            //  2,097,152 B
  f16*      Wof   = (f16*)(ws + 2506880);           // 16,384,000 B
  float*    g_buf = (float*)(ws + 18890880);        // 12,582,912 B

  k_prep<<<8481, 256, 0, stream>>>(X, Wz, bz, Wr, br, Wh, bh, Wo, g_buf, Wpack, Wof, ctl);
  k_main<<<256, 512, 0, stream>>>(H0, Wpack, g_buf, Wof, bo, Hn16, out, out + 131072000LL, ctl);
}